// Round 3
// baseline (181.976 us; speedup 1.0000x reference)
//
#include <hip/hip_runtime.h>

// COLMAP reprojection residual, gather-optimized.
// Bottleneck (R1 evidence): divergent-gather VMEM instruction throughput.
// R1: 13 divergent dword loads/thread (pose 10 + pts3 3) -> ~180us, HBM 22%,
// VALU 7.5%. Fix: repack pose into 3x float4 (q pre-normalized) and pts3 into
// float4 in d_ws -> 4 divergent dwordx4/thread. Nontemporal for one-touch
// streams to preserve L2 for the 8MB point table.
// R2 fix: nontemporal builtins need native vector types, not HIP_vector_type.

typedef float f2_t __attribute__((ext_vector_type(2)));

__global__ __launch_bounds__(256) void prep_pose(
    const float* __restrict__ pose, float4* __restrict__ pose12, int n)
{
    int i = blockIdx.x * blockDim.x + threadIdx.x;
    if (i >= n) return;
    const float* c = pose + (long)i * 10;
    float tx = c[0], ty = c[1], tz = c[2];
    float qx = c[3], qy = c[4], qz = c[5], qw = c[6];
    float f  = c[7], k1 = c[8], k2 = c[9];
    float inv = rsqrtf(qx*qx + qy*qy + qz*qz + qw*qw);
    qx *= inv; qy *= inv; qz *= inv; qw *= inv;
    pose12[i*3 + 0] = make_float4(tx, ty, tz, qx);
    pose12[i*3 + 1] = make_float4(qy, qz, qw, f);
    pose12[i*3 + 2] = make_float4(k1, k2, 0.0f, 0.0f);
}

__global__ __launch_bounds__(256) void prep_pts(
    const float* __restrict__ pts3, float4* __restrict__ pts4, int n)
{
    int i = blockIdx.x * blockDim.x + threadIdx.x;
    if (i >= n) return;
    const float* p = pts3 + (long)i * 3;
    pts4[i] = make_float4(p[0], p[1], p[2], 0.0f);
}

__global__ __launch_bounds__(256) void reproj2_kernel(
    const float* __restrict__ p2d,
    const int* __restrict__ cidx,
    const int* __restrict__ pidx,
    const float4* __restrict__ pose12,
    const float4* __restrict__ pts4,
    float* __restrict__ out,
    int M)
{
    int i = blockIdx.x * blockDim.x + threadIdx.x;
    if (i >= M) return;

    int ci = __builtin_nontemporal_load(cidx + i);
    int pi = __builtin_nontemporal_load(pidx + i);

    float4 c0 = pose12[(long)ci*3 + 0];   // tx ty tz qx
    float4 c1 = pose12[(long)ci*3 + 1];   // qy qz qw f
    float4 c2 = pose12[(long)ci*3 + 2];   // k1 k2 - -
    float4 p  = pts4[pi];                 // px py pz -

    float qx = c0.w, qy = c1.x, qz = c1.y, qw = c1.z;
    float px = p.x, py = p.y, pz = p.z;

    // uv = qv x p
    float ux = qy*pz - qz*py;
    float uy = qz*px - qx*pz;
    float uz = qx*py - qy*px;
    // w = uv + qw*p
    float wx = ux + qw*px;
    float wy = uy + qw*py;
    float wz = uz + qw*pz;
    // c = qv x w
    float cx = qy*wz - qz*wy;
    float cy = qz*wx - qx*wz;
    float cz = qx*wy - qy*wx;

    float Px = px + 2.0f*cx + c0.x;
    float Py = py + 2.0f*cy + c0.y;
    float Pz = pz + 2.0f*cz + c0.z;

    float invz = 1.0f / Pz;
    float u = Px * invz;
    float v = Py * invz;

    float n = u*u + v*v;
    float d = 1.0f + c2.x*n + c2.y*n*n;
    float s = d * c1.w;

    f2_t o = __builtin_nontemporal_load((const f2_t*)p2d + i);
    f2_t r;
    r.x = u*s - o.x;
    r.y = v*s - o.y;
    __builtin_nontemporal_store(r, (f2_t*)out + i);
}

// Fallback (ws too small): R1 direct kernel.
__global__ __launch_bounds__(256) void reproj_direct_kernel(
    const float2* __restrict__ p2d,
    const int* __restrict__ cidx,
    const int* __restrict__ pidx,
    const float* __restrict__ pose,
    const float* __restrict__ pts3,
    float2* __restrict__ out,
    int M)
{
    int i = blockIdx.x * blockDim.x + threadIdx.x;
    if (i >= M) return;
    int ci = cidx[i];
    int pi = pidx[i];
    const float* cam = pose + (long)ci * 10;
    float tx = cam[0], ty = cam[1], tz = cam[2];
    float qx = cam[3], qy = cam[4], qz = cam[5], qw = cam[6];
    float f  = cam[7], k1 = cam[8], k2 = cam[9];
    float inv = rsqrtf(qx*qx + qy*qy + qz*qz + qw*qw);
    qx *= inv; qy *= inv; qz *= inv; qw *= inv;
    const float* pp = pts3 + (long)pi * 3;
    float px = pp[0], py = pp[1], pz = pp[2];
    float ux = qy*pz - qz*py;
    float uy = qz*px - qx*pz;
    float uz = qx*py - qy*px;
    float wx = ux + qw*px;
    float wy = uy + qw*py;
    float wz = uz + qw*pz;
    float cx = qy*wz - qz*wy;
    float cy = qz*wx - qx*wz;
    float cz = qx*wy - qy*wx;
    float Px = px + 2.0f*cx + tx;
    float Py = py + 2.0f*cy + ty;
    float Pz = pz + 2.0f*cz + tz;
    float invz = 1.0f / Pz;
    float u = Px * invz;
    float v = Py * invz;
    float n = u*u + v*v;
    float d = 1.0f + k1*n + k2*n*n;
    float s = d * f;
    float2 o = p2d[i];
    out[i] = make_float2(u*s - o.x, v*s - o.y);
}

extern "C" void kernel_launch(void* const* d_in, const int* in_sizes, int n_in,
                              void* d_out, int out_size, void* d_ws, size_t ws_size,
                              hipStream_t stream) {
    const float*  p2d  = (const float*)d_in[0];
    const int*    cidx = (const int*)d_in[1];
    const int*    pidx = (const int*)d_in[2];
    const float*  pose = (const float*)d_in[3];
    const float*  pts3 = (const float*)d_in[4];

    int M      = in_sizes[1];
    int n_imgs = in_sizes[3] / 10;
    int n_pts  = in_sizes[4] / 3;

    size_t pose_bytes = (size_t)n_imgs * 48;
    size_t pose_off   = 0;
    size_t pts_off    = (pose_bytes + 255) & ~(size_t)255;
    size_t need       = pts_off + (size_t)n_pts * 16;

    int block = 256;
    if (ws_size >= need) {
        float4* pose12 = (float4*)((char*)d_ws + pose_off);
        float4* pts4   = (float4*)((char*)d_ws + pts_off);
        prep_pose<<<(n_imgs + block - 1) / block, block, 0, stream>>>(pose, pose12, n_imgs);
        prep_pts <<<(n_pts  + block - 1) / block, block, 0, stream>>>(pts3, pts4, n_pts);
        reproj2_kernel<<<(M + block - 1) / block, block, 0, stream>>>(
            p2d, cidx, pidx, pose12, pts4, (float*)d_out, M);
    } else {
        reproj_direct_kernel<<<(M + block - 1) / block, block, 0, stream>>>(
            (const float2*)p2d, cidx, pidx, pose, pts3, (float2*)d_out, M);
    }
}

// Round 4
// 116.112 us; speedup vs baseline: 1.5673x; 1.5673x over previous
//
#include <hip/hip_runtime.h>

// COLMAP reprojection residual.
// R3 evidence: time scales with divergent cache-LINE requests/lane, not VMEM
// instruction count (13->6 instrs gave only 180->167us). Fix: pose table
// staged in LDS (SoA, 8 words/cam: t,qv,f,packed-bf16 k1k2), so each obs has
// exactly 1 divergent global line request (float4 point gather). Block=1024,
// 63.5KB LDS -> 2 blocks/CU = 32 waves/CU (100% occupancy).

typedef float f2_t __attribute__((ext_vector_type(2)));

#define NCAM_MAX 2032   // 8 arrays * 2032 * 4B = 63.5 KB static LDS

__global__ __launch_bounds__(256) void prep_pts(
    const float* __restrict__ pts3, float4* __restrict__ pts4, int n)
{
    int i = blockIdx.x * blockDim.x + threadIdx.x;
    if (i >= n) return;
    const float* p = pts3 + (long)i * 3;
    pts4[i] = make_float4(p[0], p[1], p[2], 0.0f);
}

__global__ __launch_bounds__(1024) void reproj3_kernel(
    const float* __restrict__ p2d,
    const int* __restrict__ cidx,
    const int* __restrict__ pidx,
    const float* __restrict__ pose,
    const float4* __restrict__ pts4,
    float* __restrict__ out,
    int M, int n_imgs)
{
    __shared__ float s_tx[NCAM_MAX], s_ty[NCAM_MAX], s_tz[NCAM_MAX];
    __shared__ float s_qx[NCAM_MAX], s_qy[NCAM_MAX], s_qz[NCAM_MAX];
    __shared__ float s_fl[NCAM_MAX];
    __shared__ unsigned s_kk[NCAM_MAX];

    // Stage pose table: normalize q once per camera (reference does it per-obs;
    // same math). Flip sign so qw >= 0, then qw is recomputed per-obs via sqrt.
    for (int r = threadIdx.x; r < n_imgs; r += blockDim.x) {
        const float* c = pose + (long)r * 10;
        float tx = c[0], ty = c[1], tz = c[2];
        float qx = c[3], qy = c[4], qz = c[5], qw = c[6];
        float fl = c[7], k1 = c[8], k2 = c[9];
        float inv = rsqrtf(qx*qx + qy*qy + qz*qz + qw*qw);
        if (qw < 0.0f) inv = -inv;
        qx *= inv; qy *= inv; qz *= inv;
        s_tx[r] = tx; s_ty[r] = ty; s_tz[r] = tz;
        s_qx[r] = qx; s_qy[r] = qy; s_qz[r] = qz;
        s_fl[r] = fl;
        unsigned b1 = (__float_as_uint(k1) + 0x8000u) >> 16;
        unsigned b2 = (__float_as_uint(k2) + 0x8000u) >> 16;
        s_kk[r] = (b1 & 0xffffu) | ((b2 & 0xffffu) << 16);
    }
    __syncthreads();

    int stride = gridDim.x * blockDim.x;
    for (int i = blockIdx.x * blockDim.x + threadIdx.x; i < M; i += stride) {
        int ci = __builtin_nontemporal_load(cidx + i);
        int pi = __builtin_nontemporal_load(pidx + i);

        float4 p = pts4[pi];          // the single divergent global request
        float px = p.x, py = p.y, pz = p.z;

        float qx = s_qx[ci], qy = s_qy[ci], qz = s_qz[ci];
        float qw = sqrtf(fmaxf(0.0f, 1.0f - (qx*qx + qy*qy + qz*qz)));

        // uv = qv x p
        float ux = qy*pz - qz*py;
        float uy = qz*px - qx*pz;
        float uz = qx*py - qy*px;
        // w = uv + qw*p
        float wx = ux + qw*px;
        float wy = uy + qw*py;
        float wz = uz + qw*pz;
        // c = qv x w
        float cx = qy*wz - qz*wy;
        float cy = qz*wx - qx*wz;
        float cz = qx*wy - qy*wx;

        float Px = px + 2.0f*cx + s_tx[ci];
        float Py = py + 2.0f*cy + s_ty[ci];
        float Pz = pz + 2.0f*cz + s_tz[ci];

        float invz = 1.0f / Pz;
        float u = Px * invz;
        float v = Py * invz;

        unsigned kk = s_kk[ci];
        float k1 = __uint_as_float(kk << 16);
        float k2 = __uint_as_float(kk & 0xffff0000u);

        float n = u*u + v*v;
        float d = 1.0f + k1*n + k2*n*n;
        float s = d * s_fl[ci];

        f2_t o = __builtin_nontemporal_load((const f2_t*)p2d + i);
        f2_t r;
        r.x = u*s - o.x;
        r.y = v*s - o.y;
        __builtin_nontemporal_store(r, (f2_t*)out + i);
    }
}

// Fallback: direct per-obs kernel (ws too small or too many cameras).
__global__ __launch_bounds__(256) void reproj_direct_kernel(
    const float2* __restrict__ p2d,
    const int* __restrict__ cidx,
    const int* __restrict__ pidx,
    const float* __restrict__ pose,
    const float* __restrict__ pts3,
    float2* __restrict__ out,
    int M)
{
    int i = blockIdx.x * blockDim.x + threadIdx.x;
    if (i >= M) return;
    int ci = cidx[i];
    int pi = pidx[i];
    const float* cam = pose + (long)ci * 10;
    float tx = cam[0], ty = cam[1], tz = cam[2];
    float qx = cam[3], qy = cam[4], qz = cam[5], qw = cam[6];
    float f  = cam[7], k1 = cam[8], k2 = cam[9];
    float inv = rsqrtf(qx*qx + qy*qy + qz*qz + qw*qw);
    qx *= inv; qy *= inv; qz *= inv; qw *= inv;
    const float* pp = pts3 + (long)pi * 3;
    float px = pp[0], py = pp[1], pz = pp[2];
    float ux = qy*pz - qz*py;
    float uy = qz*px - qx*pz;
    float uz = qx*py - qy*px;
    float wx = ux + qw*px;
    float wy = uy + qw*py;
    float wz = uz + qw*pz;
    float cx = qy*wz - qz*wy;
    float cy = qz*wx - qx*wz;
    float cz = qx*wy - qy*wx;
    float Px = px + 2.0f*cx + tx;
    float Py = py + 2.0f*cy + ty;
    float Pz = pz + 2.0f*cz + tz;
    float invz = 1.0f / Pz;
    float u = Px * invz;
    float v = Py * invz;
    float n = u*u + v*v;
    float d = 1.0f + k1*n + k2*n*n;
    float s = d * f;
    float2 o = p2d[i];
    out[i] = make_float2(u*s - o.x, v*s - o.y);
}

extern "C" void kernel_launch(void* const* d_in, const int* in_sizes, int n_in,
                              void* d_out, int out_size, void* d_ws, size_t ws_size,
                              hipStream_t stream) {
    const float* p2d  = (const float*)d_in[0];
    const int*   cidx = (const int*)d_in[1];
    const int*   pidx = (const int*)d_in[2];
    const float* pose = (const float*)d_in[3];
    const float* pts3 = (const float*)d_in[4];

    int M      = in_sizes[1];
    int n_imgs = in_sizes[3] / 10;
    int n_pts  = in_sizes[4] / 3;

    size_t need = (size_t)n_pts * 16;

    if (ws_size >= need && n_imgs <= NCAM_MAX) {
        float4* pts4 = (float4*)d_ws;
        prep_pts<<<(n_pts + 255) / 256, 256, 0, stream>>>(pts3, pts4, n_pts);
        int block = 1024;
        int grid  = 512;   // 2 blocks/CU resident (LDS-limited), grid-stride
        reproj3_kernel<<<grid, block, 0, stream>>>(
            p2d, cidx, pidx, pose, pts4, (float*)d_out, M, n_imgs);
    } else {
        reproj_direct_kernel<<<(M + 255) / 256, 256, 0, stream>>>(
            (const float2*)p2d, cidx, pidx, pose, pts3, (float2*)d_out, M);
    }
}